// Round 1
// baseline (234.470 us; speedup 1.0000x reference)
//
#include <hip/hip_runtime.h>

// FRFT with diagonal transform matrices (Evec = I in the reference):
//   out[n,c,h,w] = D[(h+128)%256] * D[(w+128)%256] * x[n,c,h,w]
// where D[i] = 16 * exp(-i * (pi/2) * a * l_i),  l_i = i (i<255), l_255 = 256.
// Pure memory-bound elementwise complex scale. Output is complex64 ->
// interleaved (re, im) float32 pairs in d_out.

constexpr int HW = 256;              // H == W == 256
constexpr int TOTAL = 8 * 64 * 256 * 256;  // 4,194,304 elements

__global__ __launch_bounds__(256) void frft_diag_kernel(
    const float* __restrict__ x,
    const float* __restrict__ order,
    float* __restrict__ out,
    int interleaved,
    int nvec)
{
    __shared__ float tc[HW];
    __shared__ float ts[HW];

    const int t = threadIdx.x;
    // Build the shifted diagonal table once per block (256 threads -> 256 entries).
    // Double precision: phase can reach ~2400 rad; double sincos keeps the
    // argument-reduction error negligible vs the 2% absmax threshold.
    {
        const int idx = t ^ 128;                       // (t + 128) % 256
        const double l = (idx == 255) ? 256.0 : (double)idx;
        const double theta = 1.5707963267948966 * (double)order[0] * l;
        double s, c;
        sincos(theta, &s, &c);
        tc[t] = (float)(16.0 * c);                     // sqrt(256) folded per-axis
        ts[t] = (float)(16.0 * s);
    }
    __syncthreads();

    const float4* __restrict__ xv4 = (const float4*)x;
    float4* __restrict__ ov4 = (float4*)out;

    for (int v = blockIdx.x * blockDim.x + t; v < nvec; v += gridDim.x * blockDim.x) {
        const float4 xv = xv4[v];
        const int base = v << 2;                       // element index
        const int w0 = base & (HW - 1);                // 4 consecutive w, same h
        const int h  = (base >> 8) & (HW - 1);

        const float ch = tc[h];
        const float sh = ts[h];

        const float xs[4] = {xv.x, xv.y, xv.z, xv.w};
        float re[4], im[4];
        #pragma unroll
        for (int j = 0; j < 4; ++j) {
            const float cw = tc[w0 + j];
            const float sw = ts[w0 + j];
            // (ch - i*sh) * (cw - i*sw) = (ch*cw - sh*sw) - i*(ch*sw + sh*cw)
            const float pr = ch * cw - sh * sw;
            const float pi = ch * sw + sh * cw;
            re[j] =  xs[j] * pr;
            im[j] = -xs[j] * pi;
        }

        if (interleaved) {
            float4 o0 = {re[0], im[0], re[1], im[1]};
            float4 o1 = {re[2], im[2], re[3], im[3]};
            ov4[2 * v]     = o0;
            ov4[2 * v + 1] = o1;
        } else {
            float4 o = {re[0], re[1], re[2], re[3]};
            ov4[v] = o;
        }
    }
}

extern "C" void kernel_launch(void* const* d_in, const int* in_sizes, int n_in,
                              void* d_out, int out_size, void* d_ws, size_t ws_size,
                              hipStream_t stream) {
    const float* x     = (const float*)d_in[0];
    const float* order = (const float*)d_in[1];
    float* out = (float*)d_out;

    const int total = in_sizes[0];          // 4,194,304
    const int nvec  = total / 4;            // float4 vectors
    // complex64 output viewed as float32 -> expect out_size == 2*total
    const int interleaved = (out_size >= 2 * total) ? 1 : 0;

    const int block = 256;
    const int grid  = 2048;                 // 8 blocks/CU, grid-stride (2 iters)
    frft_diag_kernel<<<grid, block, 0, stream>>>(x, order, out, interleaved, nvec);
}

// Round 2
// 227.554 us; speedup vs baseline: 1.0304x; 1.0304x over previous
//
#include <hip/hip_runtime.h>

// FRFT with diagonal transform matrices (Evec = I in the reference):
//   out[n,c,h,w] = D[(h+128)%256] * D[(w+128)%256] * x[n,c,h,w]
// where D[i] = 16 * exp(-i * (pi/2) * a * l_i),  l_i = i (i<255), l_255 = 256.
// Pure memory-bound elementwise complex scale. Output complex64 ->
// interleaved (re, im) float32 pairs.
//
// Round-2 change: every memory instruction is unit-stride dense across the
// wave. Thread p loads float2 x[2p..2p+1] (8 B/lane contiguous) and stores
// one float4 {re0,im0,re1,im1} at out4[p] (16 B/lane contiguous, 1 KB/wave
// per store, no partial-line gaps). Round 1's ov4[2v]/ov4[2v+1] pair had
// 32 B lane stride -> half-masked lines -> 4x HBM traffic (201 MB vs 50 MB).

constexpr int HW = 256;  // H == W == 256

__global__ __launch_bounds__(256) void frft_diag_kernel(
    const float* __restrict__ x,
    const float* __restrict__ order,
    float* __restrict__ out,
    int interleaved,
    int nvec2)   // number of float2 input vectors = total/2
{
    __shared__ float tc[HW];
    __shared__ float ts[HW];

    const int t = threadIdx.x;
    // Build the shifted diagonal table once per block (256 threads -> 256
    // entries). Double precision: phase reaches ~2400 rad; double sincos
    // keeps argument-reduction error negligible vs the 2% threshold.
    {
        const int idx = t ^ 128;                       // (t + 128) % 256
        const double l = (idx == 255) ? 256.0 : (double)idx;
        const double theta = 1.5707963267948966 * (double)order[0] * l;
        double s, c;
        sincos(theta, &s, &c);
        tc[t] = (float)(16.0 * c);                     // sqrt(256) per axis
        ts[t] = (float)(16.0 * s);
    }
    __syncthreads();

    const int p = blockIdx.x * blockDim.x + t;         // float2 index
    if (p >= nvec2) return;

    const float2 xv = ((const float2*)x)[p];
    const int e  = p << 1;                             // element index (even)
    const int w0 = e & (HW - 1);                       // w0 <= 254, w1 = w0+1
    const int h  = (e >> 8) & (HW - 1);

    const float ch = tc[h],      sh = ts[h];
    const float c0 = tc[w0],     s0 = ts[w0];
    const float c1 = tc[w0 + 1], s1 = ts[w0 + 1];

    // (ch - i*sh)(cw - i*sw) = (ch*cw - sh*sw) - i(ch*sw + sh*cw)
    const float pr0 = ch * c0 - sh * s0;
    const float pi0 = ch * s0 + sh * c0;
    const float pr1 = ch * c1 - sh * s1;
    const float pi1 = ch * s1 + sh * c1;

    if (interleaved) {
        float4 o = { xv.x * pr0, -xv.x * pi0, xv.y * pr1, -xv.y * pi1 };
        ((float4*)out)[p] = o;
    } else {
        float2 o = { xv.x * pr0, xv.y * pr1 };
        ((float2*)out)[p] = o;
    }
}

extern "C" void kernel_launch(void* const* d_in, const int* in_sizes, int n_in,
                              void* d_out, int out_size, void* d_ws, size_t ws_size,
                              hipStream_t stream) {
    const float* x     = (const float*)d_in[0];
    const float* order = (const float*)d_in[1];
    float* out = (float*)d_out;

    const int total = in_sizes[0];          // 4,194,304
    const int nvec2 = total / 2;            // float2 vectors = 2,097,152
    const int interleaved = (out_size >= 2 * total) ? 1 : 0;

    const int block = 256;
    const int grid  = (nvec2 + block - 1) / block;   // 8192
    frft_diag_kernel<<<grid, block, 0, stream>>>(x, order, out, interleaved, nvec2);
}